// Round 1
// baseline (4045.357 us; speedup 1.0000x reference)
//
#include <hip/hip_runtime.h>
#include <stdint.h>
#include <math.h>

#define BT   65536
#define H    4
#define K    512
#define DH   256
#define BM   16
#define EPSN 1e-12f
#define EPSL 1e-10f

// ---------------------------------------------------------------------------
// ws layout (floats):
//   en_t  : [H][DH][K]      = 524288 floats (2 MiB)   offset 0
//   avgp  : [H*K]           = 2048  floats (8 KiB)    offset 524288
//   idx_ws: [BT*H] (as int) = 262144 ints  (1 MiB)    offset 526336
// total ~3.2 MiB
// ---------------------------------------------------------------------------

// Normalize emb rows (exactly like reference: x / max(sqrt(sum x^2), 1e-12)),
// store TRANSPOSED as en_t[h][d][k]; also zero the avg_probs accumulator.
__global__ __launch_bounds__(256) void vq_prep(const float* __restrict__ emb,
                                               float* __restrict__ en_t,
                                               float* __restrict__ avgp) {
  const int hk = blockIdx.x;          // h*K + k
  const int t  = threadIdx.x;         // d
  const float v = emb[(size_t)hk * DH + t];
  float s = v * v;
#pragma unroll
  for (int m = 1; m < 64; m <<= 1) s += __shfl_xor(s, m);
  __shared__ float wsum[4];
  if ((t & 63) == 0) wsum[t >> 6] = s;
  __syncthreads();
  const float tot = wsum[0] + wsum[1] + wsum[2] + wsum[3];
  const float n   = fmaxf(sqrtf(tot), EPSN);
  const int h = hk >> 9, k = hk & (K - 1);
  en_t[((size_t)h * DH + t) * K + k] = v / n;
  if (t == 0) avgp[hk] = 0.0f;
}

// Main: one block = BM(=16) b-rows for one h. 256 threads.
// Thread (c = t&7, r = t>>3) owns b = {2c, 2c+1}, k = [16r, 16r+16).
__global__ __launch_bounds__(256) void vq_main(const float* __restrict__ z_e,
                                               const float* __restrict__ emb,
                                               const float* __restrict__ scales,
                                               const float* __restrict__ en_t,
                                               float* __restrict__ avgp,
                                               int* __restrict__ idx_ws,
                                               float* __restrict__ out) {
  const int h     = blockIdx.y;
  const int bbase = blockIdx.x * BM;
  const int t     = threadIdx.x;

  __shared__ float z_t[DH][BM + 2];   // normalized z, transposed; 18 KiB
  __shared__ float red_m[4][8][2];
  __shared__ int   red_i[4][8][2];
  __shared__ float red_s[4][8][2];
  __shared__ float Sfin[BM];
  __shared__ int   Ifin[BM];

  // ---- stage z: load, L2-normalize per (b,h) like the reference, transpose ----
  {
    const int b  = t >> 4;            // 0..15
    const int j0 = (t & 15) * 16;     // 0..240
    const float* zp = z_e + (size_t)(bbase + b) * (H * DH) + h * DH + j0;
    float v[16];
    float ss = 0.0f;
#pragma unroll
    for (int u = 0; u < 16; u += 4) {
      const float4 q = *(const float4*)(zp + u);
      v[u] = q.x; v[u + 1] = q.y; v[u + 2] = q.z; v[u + 3] = q.w;
      ss += q.x * q.x + q.y * q.y + q.z * q.z + q.w * q.w;
    }
    ss += __shfl_xor(ss, 1);
    ss += __shfl_xor(ss, 2);
    ss += __shfl_xor(ss, 4);
    ss += __shfl_xor(ss, 8);
    const float n = fmaxf(sqrtf(ss), EPSN);
#pragma unroll
    for (int u = 0; u < 16; u++) z_t[j0 + u][b] = v[u] / n;
  }
  __syncthreads();

  const int c  = t & 7;
  const int r  = t >> 3;              // 0..31
  const int b0 = c * 2;
  const int k0 = r * 16;

  float acc[2][16];
#pragma unroll
  for (int i = 0; i < 2; i++)
#pragma unroll
    for (int j = 0; j < 16; j++) acc[i][j] = 0.0f;

  const float* ep = en_t + (size_t)h * DH * K + k0;
#pragma unroll 2
  for (int d = 0; d < DH; d++) {
    const float2 zz = *(const float2*)&z_t[d][b0];
    const float4 e0 = *(const float4*)(ep + 0);
    const float4 e1 = *(const float4*)(ep + 4);
    const float4 e2 = *(const float4*)(ep + 8);
    const float4 e3 = *(const float4*)(ep + 12);
    const float ev[16] = {e0.x, e0.y, e0.z, e0.w, e1.x, e1.y, e1.z, e1.w,
                          e2.x, e2.y, e2.z, e2.w, e3.x, e3.y, e3.z, e3.w};
#pragma unroll
    for (int j = 0; j < 16; j++) {
      acc[0][j] = fmaf(zz.x, ev[j], acc[0][j]);
      acc[1][j] = fmaf(zz.y, ev[j], acc[1][j]);
    }
    ep += K;
  }

  // ---- logits, thread-local argmax (first-occurrence) and exp-sum ----
  // |logit| <= ~10 so exp() never overflows; softmax needs no max-shift.
  const float sc = scales[h];
  float mx[2]; int mi[2]; float Sl[2];
#pragma unroll
  for (int i = 0; i < 2; i++) {
    mx[i] = -INFINITY; mi[i] = 0;
#pragma unroll
    for (int j = 0; j < 16; j++) {
      const float l = sc * acc[i][j];
      acc[i][j] = l;
      if (l > mx[i]) { mx[i] = l; mi[i] = k0 + j; }
    }
    Sl[i] = 0.0f;
#pragma unroll
    for (int j = 0; j < 16; j++) {
      const float e = expf(acc[i][j]);
      acc[i][j] = e;                  // acc now holds exp(logit)
      Sl[i] += e;
    }
  }

  // ---- reduce over r within wave (lanes c+8*rw): masks 8,16,32 ----
#pragma unroll
  for (int msk = 8; msk < 64; msk <<= 1) {
#pragma unroll
    for (int i = 0; i < 2; i++) {
      const float om = __shfl_xor(mx[i], msk);
      const int   oi = __shfl_xor(mi[i], msk);
      if (om > mx[i] || (om == mx[i] && oi < mi[i])) { mx[i] = om; mi[i] = oi; }
      Sl[i] += __shfl_xor(Sl[i], msk);
    }
  }
  const int wave = t >> 6, lane = t & 63;
  if (lane < 8) {
#pragma unroll
    for (int i = 0; i < 2; i++) {
      red_m[wave][lane][i] = mx[i];
      red_i[wave][lane][i] = mi[i];
      red_s[wave][lane][i] = Sl[i];
    }
  }
  __syncthreads();
  // ---- cross-wave final combine; min-index tie-break == first occurrence ----
  if (t < BM) {
    const int c2 = t >> 1, i2 = t & 1;
    float fm = -INFINITY; int fi = 0; float fs = 0.0f;
#pragma unroll
    for (int w = 0; w < 4; w++) {
      const float wm = red_m[w][c2][i2];
      const int   wi = red_i[w][c2][i2];
      if (wm > fm || (wm == fm && wi < fi)) { fm = wm; fi = wi; }
      fs += red_s[w][c2][i2];
    }
    Sfin[t] = fs;
    Ifin[t] = fi;
    idx_ws[(size_t)(bbase + t) * H + h] = fi;
  }
  __syncthreads();

  // ---- avg_probs partial: sum probs over this block's 16 b, atomic to global ----
  {
    const float r0 = 1.0f / Sfin[b0];
    const float r1 = 1.0f / Sfin[b0 + 1];
#pragma unroll
    for (int j = 0; j < 16; j++) {
      float v = acc[0][j] * r0 + acc[1][j] * r1;
      v += __shfl_xor(v, 1);
      v += __shfl_xor(v, 2);
      v += __shfl_xor(v, 4);
      if (c == 0) atomicAdd(&avgp[h * K + k0 + j], v);
    }
  }

  // ---- z_q gather: raw (un-normalized) emb rows ----
#pragma unroll 4
  for (int i = 0; i < BM; i++) {
    const int idx = Ifin[i];
    out[(size_t)(bbase + i) * (H * DH) + h * DH + t] =
        emb[((size_t)(h * K + idx)) * DH + t];
  }
}

// combined = ((idx0*512 + idx1)*512 + idx2)*512 + idx3 with int32 wraparound,
// emitted as float (the output buffer is read as float32).
__global__ __launch_bounds__(256) void vq_combined(const int* __restrict__ idx_ws,
                                                   float* __restrict__ out_comb) {
  const int b = blockIdx.x * 256 + threadIdx.x;
  if (b < BT) {
    const int* p = idx_ws + (size_t)b * H;
    uint32_t cv = (uint32_t)p[0];
    cv = cv * 512u + (uint32_t)p[1];
    cv = cv * 512u + (uint32_t)p[2];
    cv = cv * 512u + (uint32_t)p[3];
    out_comb[b] = (float)(int32_t)cv;
  }
}

__global__ __launch_bounds__(256) void vq_perp(const float* __restrict__ avgp,
                                               float* __restrict__ out_perp) {
  const int t = threadIdx.x;
  float sh[H] = {0.f, 0.f, 0.f, 0.f};
  for (int i = t; i < H * K; i += 256) {
    const int h = i >> 9;
    const float a = avgp[i] / 65536.0f;     // mean over B
    sh[h] += a * logf(a + EPSL);
  }
  __shared__ float red[4][H];
#pragma unroll
  for (int h = 0; h < H; h++) {
    float s = sh[h];
#pragma unroll
    for (int m = 1; m < 64; m <<= 1) s += __shfl_xor(s, m);
    if ((t & 63) == 0) red[t >> 6][h] = s;
  }
  __syncthreads();
  if (t == 0) {
    float p = 0.0f;
#pragma unroll
    for (int h = 0; h < H; h++) {
      const float s = red[0][h] + red[1][h] + red[2][h] + red[3][h];
      p += expf(-s);
    }
    out_perp[0] = p * 0.25f;
  }
}

extern "C" void kernel_launch(void* const* d_in, const int* in_sizes, int n_in,
                              void* d_out, int out_size, void* d_ws, size_t ws_size,
                              hipStream_t stream) {
  const float* z_e    = (const float*)d_in[0];
  const float* emb    = (const float*)d_in[1];
  const float* scales = (const float*)d_in[2];
  float* out = (float*)d_out;

  float* en_t   = (float*)d_ws;                      // 2 MiB
  float* avgp   = en_t + (size_t)H * DH * K;         // 8 KiB
  int*   idx_ws = (int*)(avgp + H * K);              // 1 MiB

  hipLaunchKernelGGL(vq_prep, dim3(H * K), dim3(256), 0, stream, emb, en_t, avgp);
  hipLaunchKernelGGL(vq_main, dim3(BT / BM, H), dim3(256), 0, stream,
                     z_e, emb, scales, en_t, avgp, idx_ws, out);
  hipLaunchKernelGGL(vq_combined, dim3(BT / 256), dim3(256), 0, stream,
                     idx_ws, out + (size_t)BT * H * DH);
  hipLaunchKernelGGL(vq_perp, dim3(1), dim3(256), 0, stream,
                     avgp, out + (size_t)BT * H * DH + BT);
}

// Round 2
// 426.118 us; speedup vs baseline: 9.4935x; 9.4935x over previous
//
#include <hip/hip_runtime.h>
#include <stdint.h>
#include <math.h>

#define BT   65536
#define H    4
#define K    512
#define DH   256
#define EPSN 1e-12f
#define EPSL 1e-10f
#define TAU  0.03f
#define CMAX 16

typedef short bf16x8 __attribute__((ext_vector_type(8)));
typedef float f32x4  __attribute__((ext_vector_type(4)));

__device__ inline unsigned short f2bf(float f) {
  uint32_t u = __builtin_bit_cast(uint32_t, f);
  u += 0x7fffu + ((u >> 16) & 1u);
  return (unsigned short)(u >> 16);
}

// ---------------------------------------------------------------------------
// ws layout (float slots):
//   en_f  : [H][K][DH] fp32 normalized      524288 floats
//   en_b  : [H][K][DH] bf16 normalized      262144 ushort = 131072 slots
//   avgp  : [H*K]                           2048
//   idx_ws: [BT][H] int                     262144
// ---------------------------------------------------------------------------

__global__ __launch_bounds__(256) void vq_prep(const float* __restrict__ emb,
                                               float* __restrict__ en_f,
                                               unsigned short* __restrict__ en_b,
                                               float* __restrict__ avgp) {
  const int hk = blockIdx.x;        // h*K + k
  const int t  = threadIdx.x;       // d
  const float v = emb[(size_t)hk * DH + t];
  float s = v * v;
#pragma unroll
  for (int m = 1; m < 64; m <<= 1) s += __shfl_xor(s, m);
  __shared__ float wsum[4];
  if ((t & 63) == 0) wsum[t >> 6] = s;
  __syncthreads();
  const float tot = wsum[0] + wsum[1] + wsum[2] + wsum[3];
  const float n   = fmaxf(sqrtf(tot), EPSN);
  const float vn  = v / n;
  en_f[(size_t)hk * DH + t] = vn;
  en_b[(size_t)hk * DH + t] = f2bf(vn);
  if (t == 0) avgp[hk] = 0.0f;
}

// Block: 64 b-rows x all 512 codes for one h. 256 threads = 4 waves.
// Wave w owns cols [128w, 128w+128): 4 (mi) x 8 (ni) 16x16 frags, K=256 in 8 steps.
__global__ __launch_bounds__(256, 2) void vq_main(
    const float* __restrict__ z_e, const float* __restrict__ scales,
    const float* __restrict__ en_f, const unsigned short* __restrict__ en_b,
    float* __restrict__ avgp, int* __restrict__ idx_ws) {
  const int h     = blockIdx.y;
  const int bbase = blockIdx.x * 64;
  const int t     = threadIdx.x;
  const int w     = t >> 6;
  const int l     = t & 63;

  __shared__ unsigned short a_lds[64 * 256];   // 32 KiB, XOR-swizzled bf16
  __shared__ float norms[64];
  __shared__ float wmaxs[4][64];
  __shared__ int   wcols[4][64];
  __shared__ float wsums[4][64];
  __shared__ float gmx[64];
  __shared__ int   gcol[64];
  __shared__ float Srow[64];
  __shared__ int   cnt[64];
  __shared__ int   cand[64][CMAX];
  __shared__ int   fidx[64];

  // ---- stage A: load z row, L2-normalize (ref: x / max(sqrt(ss),eps)), bf16->LDS ----
  {
    const int row = (w << 4) | (l >> 2);       // 0..63
    const int c4  = l & 3;
    const float* zp = z_e + (size_t)(bbase + row) * (H * DH) + h * DH;
    float4 q[16];
    float ss = 0.0f;
#pragma unroll
    for (int j = 0; j < 16; j++) {
      q[j] = *(const float4*)(zp + c4 * 4 + j * 16);
      ss += q[j].x * q[j].x + q[j].y * q[j].y + q[j].z * q[j].z + q[j].w * q[j].w;
    }
    ss += __shfl_xor(ss, 1);
    ss += __shfl_xor(ss, 2);
    const float n   = fmaxf(sqrtf(ss), EPSN);
    const float inv = 1.0f / n;
    if (c4 == 0) norms[row] = n;
    const int swz = (row & 7) << 4;
#pragma unroll
    for (int j = 0; j < 16; j++) {
      const int d = c4 * 4 + j * 16;
      uint2 pk;
      pk.x = (uint32_t)f2bf(q[j].x * inv) | ((uint32_t)f2bf(q[j].y * inv) << 16);
      pk.y = (uint32_t)f2bf(q[j].z * inv) | ((uint32_t)f2bf(q[j].w * inv) << 16);
      *(uint2*)((char*)a_lds + row * 512 + ((d * 2) ^ swz)) = pk;
    }
    if (t < 64) cnt[t] = 0;
  }
  __syncthreads();

  // ---- MFMA GEMM ----
  f32x4 acc[4][8];
#pragma unroll
  for (int mi = 0; mi < 4; mi++)
#pragma unroll
    for (int ni = 0; ni < 8; ni++) acc[mi][ni] = (f32x4){0.f, 0.f, 0.f, 0.f};

  const int arow = l & 15;
  const int kg   = l >> 4;                      // 0..3
  const int aswz = (arow & 7) << 4;
  const unsigned short* bp =
      en_b + ((size_t)(h * K) + w * 128 + arow) * DH + kg * 8;

#pragma unroll
  for (int ks = 0; ks < 8; ks++) {
    bf16x8 af[4];
#pragma unroll
    for (int mi = 0; mi < 4; mi++) {
      const int row = (mi << 4) | arow;
      const int kb  = (ks * 64) | (kg * 16);
      af[mi] = *(const bf16x8*)((const char*)a_lds + row * 512 + (kb ^ aswz));
    }
    bf16x8 bfr[8];
#pragma unroll
    for (int ni = 0; ni < 8; ni++)
      bfr[ni] = *(const bf16x8*)(bp + (size_t)ni * 16 * DH + ks * 32);
#pragma unroll
    for (int mi = 0; mi < 4; mi++)
#pragma unroll
      for (int ni = 0; ni < 8; ni++)
        acc[mi][ni] = __builtin_amdgcn_mfma_f32_16x16x32_bf16(af[mi], bfr[ni],
                                                              acc[mi][ni], 0, 0, 0);
  }

  const float sc = scales[h];
#pragma unroll
  for (int mi = 0; mi < 4; mi++)
#pragma unroll
    for (int ni = 0; ni < 8; ni++)
#pragma unroll
      for (int q = 0; q < 4; q++) acc[mi][ni][q] *= sc;

  // C layout: col = 128w + 16ni + (l&15), row = 16mi + 4*(l>>4) + q
  // ---- per-row max over this wave's 128 cols ----
  float tmx[4][4]; int tcol[4][4];
#pragma unroll
  for (int mi = 0; mi < 4; mi++)
#pragma unroll
    for (int q = 0; q < 4; q++) { tmx[mi][q] = -INFINITY; tcol[mi][q] = 1 << 30; }
#pragma unroll
  for (int mi = 0; mi < 4; mi++)
#pragma unroll
    for (int ni = 0; ni < 8; ni++) {
      const int col = w * 128 + ni * 16 + arow;
#pragma unroll
      for (int q = 0; q < 4; q++) {
        const float v = acc[mi][ni][q];
        if (v > tmx[mi][q]) { tmx[mi][q] = v; tcol[mi][q] = col; }
      }
    }
#pragma unroll
  for (int m = 1; m < 16; m <<= 1) {
#pragma unroll
    for (int mi = 0; mi < 4; mi++)
#pragma unroll
      for (int q = 0; q < 4; q++) {
        const float om = __shfl_xor(tmx[mi][q], m);
        const int   oc = __shfl_xor(tcol[mi][q], m);
        if (om > tmx[mi][q] || (om == tmx[mi][q] && oc < tcol[mi][q])) {
          tmx[mi][q] = om; tcol[mi][q] = oc;
        }
      }
  }
  if (arow == 0) {
#pragma unroll
    for (int mi = 0; mi < 4; mi++)
#pragma unroll
      for (int q = 0; q < 4; q++) {
        const int row = 16 * mi + 4 * kg + q;
        wmaxs[w][row] = tmx[mi][q];
        wcols[w][row] = tcol[mi][q];
      }
  }
  __syncthreads();
  if (t < 64) {
    float m = -INFINITY; int c = 1 << 30;
#pragma unroll
    for (int ww = 0; ww < 4; ww++) {
      const float vm = wmaxs[ww][t];
      const int   vc = wcols[ww][t];
      if (vm > m || (vm == m && vc < c)) { m = vm; c = vc; }
    }
    gmx[t] = m; gcol[t] = c;
  }
  __syncthreads();

  // ---- candidate scan: approx logit >= gmax - TAU ----
#pragma unroll
  for (int mi = 0; mi < 4; mi++)
#pragma unroll
    for (int ni = 0; ni < 8; ni++) {
      const int col = w * 128 + ni * 16 + arow;
#pragma unroll
      for (int q = 0; q < 4; q++) {
        const int row = 16 * mi + 4 * kg + q;
        if (acc[mi][ni][q] >= gmx[row] - TAU) {
          const int p = atomicAdd(&cnt[row], 1);
          if (p < CMAX) cand[row][p] = col;
        }
      }
    }
  __syncthreads();

  // ---- refine: exact fp32 dot for multi-candidate rows (64-lane cooperative) ----
  for (int r = w; r < 64; r += 4) {
    int c = cnt[r];
    int best;
    if (c <= 1) {
      best = gcol[r];
    } else {
      if (c > CMAX) c = CMAX;
      const float nrm = norms[r];
      const float4 zq = *(const float4*)(z_e + (size_t)(bbase + r) * (H * DH) +
                                         h * DH + l * 4);
      const float zn0 = zq.x / nrm, zn1 = zq.y / nrm,
                  zn2 = zq.z / nrm, zn3 = zq.w / nrm;
      float bv = -INFINITY; int bi = 1 << 30;
      for (int i = 0; i < c; i++) {
        const int cc = cand[r][i];
        const float4 eq = *(const float4*)(en_f + ((size_t)(h * K) + cc) * DH + l * 4);
        float d0 = fmaf(zn0, eq.x, fmaf(zn1, eq.y, fmaf(zn2, eq.z, zn3 * eq.w)));
#pragma unroll
        for (int m = 1; m < 64; m <<= 1) d0 += __shfl_xor(d0, m);
        const float val = sc * d0;
        if (val > bv || (val == bv && cc < bi)) { bv = val; bi = cc; }
      }
      best = bi;
    }
    if (l == 0) fidx[r] = best;
  }

  // ---- exp in place + per-row sums (|logit|<=~10: no max shift needed) ----
  float tsum[4][4];
#pragma unroll
  for (int mi = 0; mi < 4; mi++)
#pragma unroll
    for (int q = 0; q < 4; q++) tsum[mi][q] = 0.0f;
#pragma unroll
  for (int mi = 0; mi < 4; mi++)
#pragma unroll
    for (int ni = 0; ni < 8; ni++)
#pragma unroll
      for (int q = 0; q < 4; q++) {
        const float e = __expf(acc[mi][ni][q]);
        acc[mi][ni][q] = e;
        tsum[mi][q] += e;
      }
#pragma unroll
  for (int m = 1; m < 16; m <<= 1)
#pragma unroll
    for (int mi = 0; mi < 4; mi++)
#pragma unroll
      for (int q = 0; q < 4; q++) tsum[mi][q] += __shfl_xor(tsum[mi][q], m);
  if (arow == 0) {
#pragma unroll
    for (int mi = 0; mi < 4; mi++)
#pragma unroll
      for (int q = 0; q < 4; q++) wsums[w][16 * mi + 4 * kg + q] = tsum[mi][q];
  }
  __syncthreads();
  if (t < 64) Srow[t] = wsums[0][t] + wsums[1][t] + wsums[2][t] + wsums[3][t];
  __syncthreads();

  // ---- avg_probs partial (per-col sum over 64 rows) + idx write ----
#pragma unroll
  for (int ni = 0; ni < 8; ni++) {
    float v = 0.0f;
#pragma unroll
    for (int mi = 0; mi < 4; mi++)
#pragma unroll
      for (int q = 0; q < 4; q++)
        v += acc[mi][ni][q] / Srow[16 * mi + 4 * kg + q];
    v += __shfl_xor(v, 16);
    v += __shfl_xor(v, 32);
    if (l < 16) atomicAdd(&avgp[h * K + w * 128 + ni * 16 + arow], v);
  }
  if (t < 64) idx_ws[(size_t)(bbase + t) * H + h] = fidx[t];
}

// z_q gather: 16 b-rows per block, coalesced 1 KiB per wave per row segment.
__global__ __launch_bounds__(256) void vq_gather(const float* __restrict__ emb,
                                                 const int* __restrict__ idx_ws,
                                                 float* __restrict__ out) {
  const int t  = threadIdx.x;
  const int h  = t >> 6;
  const int d  = (t & 63) * 4;
  const int b0 = blockIdx.x * 16;
#pragma unroll 4
  for (int i = 0; i < 16; i++) {
    const int b   = b0 + i;
    const int idx = idx_ws[(size_t)b * H + h];
    const float4 v = *(const float4*)(emb + ((size_t)(h * K) + idx) * DH + d);
    *(float4*)(out + (size_t)b * (H * DH) + h * DH + d) = v;
  }
}

__global__ __launch_bounds__(256) void vq_combined(const int* __restrict__ idx_ws,
                                                   float* __restrict__ out_comb) {
  const int b = blockIdx.x * 256 + threadIdx.x;
  if (b < BT) {
    const int* p = idx_ws + (size_t)b * H;
    uint32_t cv = (uint32_t)p[0];
    cv = cv * 512u + (uint32_t)p[1];
    cv = cv * 512u + (uint32_t)p[2];
    cv = cv * 512u + (uint32_t)p[3];
    out_comb[b] = (float)(int32_t)cv;
  }
}

__global__ __launch_bounds__(256) void vq_perp(const float* __restrict__ avgp,
                                               float* __restrict__ out_perp) {
  const int t = threadIdx.x;
  float sh[H] = {0.f, 0.f, 0.f, 0.f};
  for (int i = t; i < H * K; i += 256) {
    const int h = i >> 9;
    const float a = avgp[i] / 65536.0f;
    sh[h] += a * logf(a + EPSL);
  }
  __shared__ float red[4][H];
#pragma unroll
  for (int h = 0; h < H; h++) {
    float s = sh[h];
#pragma unroll
    for (int m = 1; m < 64; m <<= 1) s += __shfl_xor(s, m);
    if ((t & 63) == 0) red[t >> 6][h] = s;
  }
  __syncthreads();
  if (t == 0) {
    float p = 0.0f;
#pragma unroll
    for (int h = 0; h < H; h++) {
      const float s = red[0][h] + red[1][h] + red[2][h] + red[3][h];
      p += expf(-s);
    }
    out_perp[0] = p * 0.25f;
  }
}

extern "C" void kernel_launch(void* const* d_in, const int* in_sizes, int n_in,
                              void* d_out, int out_size, void* d_ws, size_t ws_size,
                              hipStream_t stream) {
  const float* z_e    = (const float*)d_in[0];
  const float* emb    = (const float*)d_in[1];
  const float* scales = (const float*)d_in[2];
  float* out = (float*)d_out;

  float*          en_f   = (float*)d_ws;                       // 524288 floats
  unsigned short* en_b   = (unsigned short*)(en_f + (size_t)H * K * DH);
  float*          avgp   = (float*)(en_b + (size_t)H * K * DH); // 2048 floats
  int*            idx_ws = (int*)(avgp + H * K);                // 262144 ints

  hipLaunchKernelGGL(vq_prep, dim3(H * K), dim3(256), 0, stream,
                     emb, en_f, en_b, avgp);
  hipLaunchKernelGGL(vq_main, dim3(BT / 64, H), dim3(256), 0, stream,
                     z_e, scales, en_f, en_b, avgp, idx_ws);
  hipLaunchKernelGGL(vq_gather, dim3(BT / 16), dim3(256), 0, stream,
                     emb, idx_ws, out);
  hipLaunchKernelGGL(vq_combined, dim3(BT / 256), dim3(256), 0, stream,
                     idx_ws, out + (size_t)BT * H * DH);
  hipLaunchKernelGGL(vq_perp, dim3(1), dim3(256), 0, stream,
                     avgp, out + (size_t)BT * H * DH + BT);
}